// Round 1
// baseline (416.542 us; speedup 1.0000x reference)
//
#include <hip/hip_runtime.h>

// LSTM: B=1024, S=512, E=H=50, fp32 in/out.
// Grid: 256 blocks x 256 threads (4 waves). Each block owns 4 batch chains for all 512 steps.
// gates(16x16 tiles) = W_reordered(208x128, bf16 hi/lo in VGPRs) @ [x;h] (128x16, bf16 in LDS).
// Gate reorder j = h*4 + g  ->  each lane's 4 acc regs are {i,f,g,o} for one (chain,h): lane-local LSTM cell update.
// K layout: k 0-49 = x, 50-63 = 0-pad, 64-113 = h, 114-127 = 0-pad  (x and h in separate K-tiles -> independent ring buffers).

typedef __attribute__((ext_vector_type(8))) short s16x8;   // 8 x bf16 (guide-verified operand type for gfx950 mfma)
typedef __attribute__((ext_vector_type(4))) float f32x4;

__device__ __forceinline__ unsigned short f2bf(float f) {  // RNE f32->bf16
  unsigned u = __float_as_uint(f);
  u = u + 0x7fffu + ((u >> 16) & 1u);
  return (unsigned short)(u >> 16);
}
__device__ __forceinline__ float bf2f(unsigned short b) {
  return __uint_as_float(((unsigned)b) << 16);
}
__device__ __forceinline__ float fast_sigmoid(float z) {
  return __builtin_amdgcn_rcpf(1.0f + __expf(-z));
}
__device__ __forceinline__ float fast_tanh(float z) {
  return 1.0f - 2.0f * __builtin_amdgcn_rcpf(1.0f + __expf(2.0f * z));
}

__global__ __launch_bounds__(256, 1) void lstm_fused(
    const float* __restrict__ xg,     // (1024, 512, 50)
    const float* __restrict__ W_ih,   // (200, 50)
    const float* __restrict__ W_hh,   // (200, 50)
    const float* __restrict__ b_ih,   // (200,)
    const float* __restrict__ b_hh,   // (200,)
    float* __restrict__ out)          // (1024, 1, 50)
{
  constexpr int S = 512, E = 50, H = 50;
  const int tid  = threadIdx.x;
  const int lane = tid & 63;
  const int wv   = tid >> 6;
  const int c0   = blockIdx.x << 2;   // first of 4 chains

  // LDS: xbuf ring[4 slots][2 kt][4 chains][64B]  = 2048 B
  //      hbuf ring[2 slots][2 kt][4 chains][64B]  = 1024 B  (at +2048)
  __shared__ __align__(16) unsigned char lds[3072];
  for (int i = tid; i < 3072 / 4; i += 256) reinterpret_cast<unsigned*>(lds)[i] = 0u;

  const int m  = lane & 15;   // gate-row within M-tile (A m-index), also D col for B
  const int kg = lane >> 4;   // k-group of 8 for A/B operands; D row-group
  const int tstart = (wv == 0) ? 0 : (3 * wv + 1);  // tiles {0-3},{4-6},{7-9},{10-12}
  const int tcnt   = (wv == 0) ? 4 : 3;

  // ---- W fragments: register-stationary for all 512 steps (bf16 hi + lo pair) ----
  s16x8 whi[4][4], wlo[4][4];
  f32x4 bias[4];
#pragma unroll
  for (int i = 0; i < 4; ++i) {
    const int  mt    = tstart + i;
    const bool tv    = (i < tcnt);
    const int  j     = mt * 16 + m;     // reordered gate idx = h*4 + g
    const int  hh    = j >> 2, g = j & 3;
    const bool rowok = tv && (hh < H);
#pragma unroll
    for (int kt = 0; kt < 4; ++kt) {
      s16x8 shi, slo;
#pragma unroll
      for (int jj = 0; jj < 8; ++jj) {
        const int k = kt * 32 + kg * 8 + jj;
        float w = 0.0f;
        if (rowok) {
          if (k < 50)                 w = W_ih[(g * 50 + hh) * 50 + k];
          else if (k >= 64 && k < 114) w = W_hh[(g * 50 + hh) * 50 + (k - 64)];
        }
        const unsigned short hb = f2bf(w);
        shi[jj] = (short)hb;
        slo[jj] = (short)f2bf(w - bf2f(hb));
      }
      whi[i][kt] = shi;
      wlo[i][kt] = slo;
    }
    f32x4 bv;
#pragma unroll
    for (int r = 0; r < 4; ++r) {
      const int jr = mt * 16 + kg * 4 + r;   // D row = kg*4 + r
      const int hr = jr >> 2, gr = jr & 3;
      bv[r] = (tv && hr < H) ? (b_ih[gr * 50 + hr] + b_hh[gr * 50 + hr]) : 0.0f;
    }
    bias[i] = bv;
  }

  // ---- x prefetch mapping: threads 0..199 each own one (chain,e) ----
  const int  xc   = tid / 50;
  const int  xe   = tid - xc * 50;
  const bool xok  = (tid < 200);
  const long xbase = ((long)(c0 + xc) * S) * E + xe;
  const int  xoff  = ((xe >> 5) << 8) + (xc << 6) + ((xe & 31) << 1);

  __syncthreads();   // zeros visible (pads + h0 = 0)
  if (xok) {
    *reinterpret_cast<unsigned short*>(lds + 0 * 512 + xoff) = f2bf(xg[xbase + 0 * E]);
    *reinterpret_cast<unsigned short*>(lds + 1 * 512 + xoff) = f2bf(xg[xbase + 1 * E]);
  }
  float xra = 0.f, xrb = 0.f, xrc = 0.f, xrd = 0.f;   // 2-step-deep prefetch regs
  if (xok) { xra = xg[xbase + 2 * E]; xrb = xg[xbase + 3 * E]; }
  __syncthreads();

  float cst[4] = {0.f, 0.f, 0.f, 0.f};               // c state, lane-resident
  const int  bc      = lane & 3;                      // effective chain (cols 4-15 duplicate 0-3, unused)
  const bool actlane = (m < 4);                       // lanes holding real chains' D columns
  const unsigned bro = (unsigned)(bc << 6) + (unsigned)(kg << 4);

  auto step = [&](int t, float& P, float& Q) {
    // issue x[t+4] early (lands ~2 steps later)
    if (xok && (t + 4) < S) Q = xg[xbase + (t + 4) * E];

    const unsigned xs = (unsigned)(t & 3) * 512u;
    const unsigned hs = 2048u + (unsigned)(t & 1) * 512u;
    const s16x8 b0 = *reinterpret_cast<const s16x8*>(lds + xs + bro);
    const s16x8 b1 = *reinterpret_cast<const s16x8*>(lds + xs + 256u + bro);
    const s16x8 b2 = *reinterpret_cast<const s16x8*>(lds + hs + bro);
    const s16x8 b3 = *reinterpret_cast<const s16x8*>(lds + hs + 256u + bro);

    f32x4 acc[4];
#pragma unroll
    for (int i = 0; i < 4; ++i) {
      f32x4 a = bias[i];
      a = __builtin_amdgcn_mfma_f32_16x16x32_bf16(whi[i][0], b0, a, 0, 0, 0);
      a = __builtin_amdgcn_mfma_f32_16x16x32_bf16(wlo[i][0], b0, a, 0, 0, 0);
      a = __builtin_amdgcn_mfma_f32_16x16x32_bf16(whi[i][1], b1, a, 0, 0, 0);
      a = __builtin_amdgcn_mfma_f32_16x16x32_bf16(wlo[i][1], b1, a, 0, 0, 0);
      a = __builtin_amdgcn_mfma_f32_16x16x32_bf16(whi[i][2], b2, a, 0, 0, 0);
      a = __builtin_amdgcn_mfma_f32_16x16x32_bf16(wlo[i][2], b2, a, 0, 0, 0);
      a = __builtin_amdgcn_mfma_f32_16x16x32_bf16(whi[i][3], b3, a, 0, 0, 0);
      a = __builtin_amdgcn_mfma_f32_16x16x32_bf16(wlo[i][3], b3, a, 0, 0, 0);
      acc[i] = a;
    }

    if (actlane) {
#pragma unroll
      for (int i = 0; i < 4; ++i) {
        const int hix = 4 * (tstart + i) + kg;
        if (i < tcnt && hix < H) {
          const float ig = fast_sigmoid(acc[i][0]);   // reg r = gate type (i,f,g,o)
          const float fg = fast_sigmoid(acc[i][1]);
          const float gg = fast_tanh   (acc[i][2]);
          const float og = fast_sigmoid(acc[i][3]);
          const float c  = fg * cst[i] + ig * gg;
          cst[i] = c;
          const float hv = og * fast_tanh(c);
          if (t == S - 1) {
            out[(long)(c0 + bc) * H + hix] = hv;      // final h, fp32
          } else {
            const int kth = hix >> 5, kl = hix & 31;
            *reinterpret_cast<unsigned short*>(
                lds + 2048u + (unsigned)((t + 1) & 1) * 512u +
                (unsigned)(kth << 8) + (unsigned)(bc << 6) + (unsigned)(kl << 1)) = f2bf(hv);
          }
        }
      }
    }

    // write x[t+2] (issued 2 steps ago) into its ring slot
    if (xok && (t + 2) < S) {
      *reinterpret_cast<unsigned short*>(lds + (unsigned)((t + 2) & 3) * 512u + xoff) = f2bf(P);
    }
    __syncthreads();   // slots t+1 complete before next step reads
  };

  for (int t = 0; t < S; t += 4) {
    step(t + 0, xra, xrc);
    step(t + 1, xrb, xrd);
    step(t + 2, xrc, xra);
    step(t + 3, xrd, xrb);
  }
}

extern "C" void kernel_launch(void* const* d_in, const int* in_sizes, int n_in,
                              void* d_out, int out_size, void* d_ws, size_t ws_size,
                              hipStream_t stream) {
  const float* x    = (const float*)d_in[0];
  const float* W_ih = (const float*)d_in[1];
  const float* W_hh = (const float*)d_in[2];
  const float* b_ih = (const float*)d_in[3];
  const float* b_hh = (const float*)d_in[4];
  float* out = (float*)d_out;
  hipLaunchKernelGGL(lstm_fused, dim3(256), dim3(256), 0, stream,
                     x, W_ih, W_hh, b_ih, b_hh, out);
}

// Round 4
// 363.086 us; speedup vs baseline: 1.1472x; 1.1472x over previous
//
#include <hip/hip_runtime.h>

// LSTM: B=1024, S=512, E=H=50, fp32 in/out.
// Grid: 256 blocks x 256 threads (4 waves). Each block owns 4 batch chains for all 512 steps.
// gates(16x16 tiles) = W_reordered(208x128, fp16 in VGPRs) @ [x;h] (128x16, fp16 in LDS).
// Gate reorder j = h*4 + g  ->  each lane's 4 acc regs are {i,f,g,o} for one (chain,h): lane-local cell update.
// K layout: k 0-49 = x, 50-63 = 0-pad, 64-113 = h, 114-127 = 0-pad.
// Software pipeline: x-part of step t+1 (xnxt) computed during step t, off the h-recurrence critical path.

typedef __attribute__((ext_vector_type(8))) _Float16 f16x8;  // 8 x fp16 (4 VGPRs) MFMA operand
typedef __attribute__((ext_vector_type(4))) float f32x4;

__device__ __forceinline__ float fast_sigmoid(float z) {
  return __builtin_amdgcn_rcpf(1.0f + __expf(-z));
}
__device__ __forceinline__ float fast_tanh(float z) {
  return 1.0f - 2.0f * __builtin_amdgcn_rcpf(1.0f + __expf(2.0f * z));
}

__global__ __launch_bounds__(256, 1) void lstm_fused(
    const float* __restrict__ xg,     // (1024, 512, 50)
    const float* __restrict__ W_ih,   // (200, 50)
    const float* __restrict__ W_hh,   // (200, 50)
    const float* __restrict__ b_ih,   // (200,)
    const float* __restrict__ b_hh,   // (200,)
    float* __restrict__ out)          // (1024, 1, 50)
{
  constexpr int S = 512, E = 50, H = 50;
  const int tid  = threadIdx.x;
  const int lane = tid & 63;
  const int wv   = tid >> 6;
  const int c0   = blockIdx.x << 2;   // first of 4 chains

  // LDS: xbuf ring[4 slots][2 kt][4 chains][64B]  = 2048 B
  //      hbuf ring[2 slots][2 kt][4 chains][64B]  = 1024 B  (at +2048)
  __shared__ __align__(16) unsigned char lds[3072];
  for (int i = tid; i < 3072 / 4; i += 256) reinterpret_cast<unsigned*>(lds)[i] = 0u;

  const int m  = lane & 15;   // gate-row within M-tile (A m-index), also D col for B
  const int kg = lane >> 4;   // k-group of 8 for A/B operands; D row-group
  const int tstart = (wv == 0) ? 0 : (3 * wv + 1);  // tiles {0-3},{4-6},{7-9},{10-12}
  const int tcnt   = (wv == 0) ? 4 : 3;

  // ---- W fragments: register-stationary fp16 for all 512 steps ----
  f16x8 wfr[4][4];
  f32x4 bias[4];
#pragma unroll
  for (int i = 0; i < 4; ++i) {
    const int  mt    = tstart + i;
    const bool tv    = (i < tcnt);
    const int  j     = mt * 16 + m;     // reordered gate idx = h*4 + g
    const int  hh    = j >> 2, g = j & 3;
    const bool rowok = tv && (hh < H);
#pragma unroll
    for (int kt = 0; kt < 4; ++kt) {
      f16x8 s;
#pragma unroll
      for (int jj = 0; jj < 8; ++jj) {
        const int k = kt * 32 + kg * 8 + jj;
        float w = 0.0f;
        if (rowok) {
          if (k < 50)                  w = W_ih[(g * 50 + hh) * 50 + k];
          else if (k >= 64 && k < 114) w = W_hh[(g * 50 + hh) * 50 + (k - 64)];
        }
        s[jj] = (_Float16)w;
      }
      wfr[i][kt] = s;
    }
    f32x4 bv;
#pragma unroll
    for (int r = 0; r < 4; ++r) {
      const int jr = mt * 16 + kg * 4 + r;   // D row = kg*4 + r
      const int hr = jr >> 2, gr = jr & 3;
      bv[r] = (tv && hr < H) ? (b_ih[gr * 50 + hr] + b_hh[gr * 50 + hr]) : 0.0f;
    }
    bias[i] = bv;
  }

  // ---- x prefetch mapping: threads 0..199 each own one (chain,e) ----
  const int  xc   = tid / 50;
  const int  xe   = tid - xc * 50;
  const bool xok  = (tid < 200);
  const long xbase = ((long)(c0 + xc) * S) * E + xe;
  const int  xoff  = ((xe >> 5) << 8) + (xc << 6) + ((xe & 31) << 1);

  __syncthreads();   // zeros visible (pads + h0 = 0)
  if (xok) {
    *reinterpret_cast<_Float16*>(lds + 0 * 512 + xoff) = (_Float16)xg[xbase + 0 * E];
    *reinterpret_cast<_Float16*>(lds + 1 * 512 + xoff) = (_Float16)xg[xbase + 1 * E];
  }
  float xra = 0.f, xrb = 0.f, xrc = 0.f, xrd = 0.f;   // 2-step-deep prefetch regs
  if (xok) { xra = xg[xbase + 2 * E]; xrb = xg[xbase + 3 * E]; }
  __syncthreads();

  float cst[4] = {0.f, 0.f, 0.f, 0.f};               // c state, lane-resident
  const int  bc      = lane & 3;                      // effective chain (cols 4-15 duplicate 0-3, unused)
  const bool actlane = (m < 4);                       // lanes holding real chains' D columns
  const unsigned bro = (unsigned)(bc << 6) + (unsigned)(kg << 4);

  // ---- prime xcur = bias + W_x @ x[0] (slot 0) ----
  f32x4 xcur[4];
  {
    const f16x8 b0 = *reinterpret_cast<const f16x8*>(lds + 0u + bro);
    const f16x8 b1 = *reinterpret_cast<const f16x8*>(lds + 256u + bro);
#pragma unroll
    for (int i = 0; i < 4; ++i) {
      f32x4 a = bias[i];
      a = __builtin_amdgcn_mfma_f32_16x16x32_f16(wfr[i][0], b0, a, 0, 0, 0);
      a = __builtin_amdgcn_mfma_f32_16x16x32_f16(wfr[i][1], b1, a, 0, 0, 0);
      xcur[i] = a;
    }
  }

  auto step = [&](int t, float& P, float& Q) {
    // issue x[t+4] early (lands ~2 steps later)
    if (xok && (t + 4) < S) Q = xg[xbase + (t + 4) * E];

    const unsigned hs = 2048u + (unsigned)(t & 1) * 512u;
    const unsigned xs = (unsigned)((t + 1) & 3) * 512u;   // x slot for step t+1
    const f16x8 b2  = *reinterpret_cast<const f16x8*>(lds + hs + bro);
    const f16x8 b3  = *reinterpret_cast<const f16x8*>(lds + hs + 256u + bro);
    const f16x8 nb0 = *reinterpret_cast<const f16x8*>(lds + xs + bro);
    const f16x8 nb1 = *reinterpret_cast<const f16x8*>(lds + xs + 256u + bro);

    // critical path: h-part, chain depth 2, C-in = precomputed x-part
    f32x4 acc[4];
#pragma unroll
    for (int i = 0; i < 4; ++i) {
      f32x4 a = xcur[i];
      a = __builtin_amdgcn_mfma_f32_16x16x32_f16(wfr[i][2], b2, a, 0, 0, 0);
      a = __builtin_amdgcn_mfma_f32_16x16x32_f16(wfr[i][3], b3, a, 0, 0, 0);
      acc[i] = a;
    }

    if (actlane) {
#pragma unroll
      for (int i = 0; i < 4; ++i) {
        const int hix = 4 * (tstart + i) + kg;
        if (i < tcnt && hix < H) {
          const float ig = fast_sigmoid(acc[i][0]);   // reg r = gate type (i,f,g,o)
          const float fg = fast_sigmoid(acc[i][1]);
          const float gg = fast_tanh   (acc[i][2]);
          const float og = fast_sigmoid(acc[i][3]);
          const float c  = fg * cst[i] + ig * gg;
          cst[i] = c;
          const float hv = og * fast_tanh(c);
          if (t == S - 1) {
            out[(long)(c0 + bc) * H + hix] = hv;      // final h, fp32
          } else {
            const int kth = hix >> 5, kl = hix & 31;
            *reinterpret_cast<_Float16*>(
                lds + 2048u + (unsigned)((t + 1) & 1) * 512u +
                (unsigned)(kth << 8) + (unsigned)(bc << 6) + (unsigned)(kl << 1)) = (_Float16)hv;
          }
        }
      }
    }

    // off-critical-path: x-part for step t+1 (x[t+1] resident since step t-1)
#pragma unroll
    for (int i = 0; i < 4; ++i) {
      f32x4 a = bias[i];
      a = __builtin_amdgcn_mfma_f32_16x16x32_f16(wfr[i][0], nb0, a, 0, 0, 0);
      a = __builtin_amdgcn_mfma_f32_16x16x32_f16(wfr[i][1], nb1, a, 0, 0, 0);
      xcur[i] = a;
    }

    // write x[t+2] (issued 2 steps ago) into its ring slot
    if (xok && (t + 2) < S) {
      *reinterpret_cast<_Float16*>(lds + (unsigned)((t + 2) & 3) * 512u + xoff) = (_Float16)P;
    }
    __syncthreads();   // slot t+1 (h and x) complete before next step reads
  };

  for (int t = 0; t < S; t += 4) {
    step(t + 0, xra, xrc);
    step(t + 1, xrb, xrd);
    step(t + 2, xrc, xra);
    step(t + 3, xrd, xrb);
  }
}

extern "C" void kernel_launch(void* const* d_in, const int* in_sizes, int n_in,
                              void* d_out, int out_size, void* d_ws, size_t ws_size,
                              hipStream_t stream) {
  const float* x    = (const float*)d_in[0];
  const float* W_ih = (const float*)d_in[1];
  const float* W_hh = (const float*)d_in[2];
  const float* b_ih = (const float*)d_in[3];
  const float* b_hh = (const float*)d_in[4];
  float* out = (float*)d_out;
  hipLaunchKernelGGL(lstm_fused, dim3(256), dim3(256), 0, stream,
                     x, W_ih, W_hh, b_ih, b_hh, out);
}